// Round 5
// baseline (540.844 us; speedup 1.0000x reference)
//
#include <hip/hip_runtime.h>
#include <hip/hip_bf16.h>
#include <math.h>

#define C1N 128
#define HA 200
#define WA 200
#define HBB 100
#define WBB 360
#define GH 200
#define GW 360
#define NHD 8
#define HDD 16

typedef __attribute__((ext_vector_type(8))) short short8;
typedef __attribute__((ext_vector_type(4))) float f32x4;
typedef __attribute__((ext_vector_type(16))) float f32x16;

__device__ __forceinline__ float bf2f(unsigned short u) {
  union { unsigned int i; float f; } c; c.i = ((unsigned int)u) << 16; return c.f;
}
__device__ __forceinline__ unsigned short f2bf(float f) {
  __hip_bfloat16 h = __float2bfloat16(f);
  unsigned short u;
  __builtin_memcpy(&u, &h, sizeof(u));
  return u;
}

// ---- coordinate pipeline: must match numpy f32 op-for-op. ----
__device__ __forceinline__ void polar_xy(float fov, int i, int j, float& x, float& y) {
#pragma clang fp contract(off)
  float t = (float)j / 359.0f;
  float angle = -fov / 2.0f + fov * t;
  float ca = (float)cos((double)angle);
  float sa = (float)sin((double)angle);
  float rmax = fminf(100.0f / fabsf(ca), 100.0f / fabsf(sa));
  float r = ((float)i / 199.0f) * rmax;
  float xv = 100.0f + r * ca;
  float yv = 100.0f - r * sa;
  x = fminf(fmaxf(xv, 0.0f), 199.0f);
  y = fminf(fmaxf(yv, 0.0f), 199.0f);
}

// Fused weights in bf16: Wb[w<3] = (in_proj_w[w] @ {Wq,Wk,Wv}) ; Wb[3] = out_w.
__global__ void weff_k(const float* __restrict__ Wq, const float* __restrict__ Wk,
                       const float* __restrict__ Wv, const float* __restrict__ bq,
                       const float* __restrict__ bk, const float* __restrict__ bv,
                       const float* __restrict__ inw, const float* __restrict__ inb,
                       const float* __restrict__ outw, const float* __restrict__ outb,
                       __hip_bfloat16* __restrict__ Wb, float* __restrict__ beff) {
  int which = blockIdx.y;
  int o = blockIdx.x;
  int kcol = threadIdx.x;
  if (which == 3) {
    Wb[3 * 16384 + o * 128 + kcol] = __float2bfloat16(outw[o * 128 + kcol]);
    if (kcol == 0) beff[384 + o] = outb[o];
    return;
  }
  const float* Wx = (which == 0) ? Wq : ((which == 1) ? Wk : Wv);
  const float* bx = (which == 0) ? bq : ((which == 1) ? bk : bv);
  const float* wrow = inw + (which * 128 + o) * 128;
  float acc = 0.0f;
  for (int m = 0; m < 128; ++m) acc += wrow[m] * Wx[m * 128 + kcol];
  Wb[which * 16384 + o * 128 + kcol] = __float2bfloat16(acc);
  if (kcol == 0) {
    float bacc = inb[which * 128 + o];
    for (int m = 0; m < 128; ++m) bacc += wrow[m] * bx[m];
    beff[which * 128 + o] = bacc;
  }
}

// a (128,200,200) f32 -> aT[(y*200+x)*128 + c] bf16. LDS 32x32 tiles.
__global__ __launch_bounds__(256) void transA_k(const float* __restrict__ a,
                                                __hip_bfloat16* __restrict__ aT) {
  __shared__ float tile[32][33];
  int p0 = blockIdx.x * 32, c0 = blockIdx.y * 32;
  int tp = threadIdx.x & 31, tr = threadIdx.x >> 5;
  for (int cc = tr; cc < 32; cc += 8)
    tile[cc][tp] = a[(size_t)(c0 + cc) * 40000 + p0 + tp];
  __syncthreads();
  for (int pp = tr; pp < 32; pp += 8)
    aT[(size_t)(p0 + pp) * C1N + c0 + tp] = __float2bfloat16(tile[tp][pp]);
}

// Coalesced bilinear from aT (bf16 p-major).
__global__ __launch_bounds__(256) void bilinear2_k(const __hip_bfloat16* __restrict__ aT,
                                                   const float* __restrict__ fovp, int n,
                                                   __hip_bfloat16* __restrict__ aseq) {
  __shared__ float sw[20][4];
  __shared__ int sp[20][4];
  int j = blockIdx.x;
  int i_base = blockIdx.y * 20;
  int t = threadIdx.x;
  if (t < 20) {
    float x, y;
    polar_xy(fovp[n], i_base + t, j, x, y);
    float x0f = floorf(x), y0f = floorf(y);
    float wx = x - x0f, wy = y - y0f;
    int x0 = max(0, min(199, (int)x0f));
    int x1 = min(x0 + 1, 199);
    int y0 = max(0, min(199, (int)y0f));
    int y1 = min(y0 + 1, 199);
    sp[t][0] = y0 * 200 + x0; sp[t][1] = y0 * 200 + x1;
    sp[t][2] = y1 * 200 + x0; sp[t][3] = y1 * 200 + x1;
    sw[t][0] = (1.0f - wx) * (1.0f - wy); sw[t][1] = wx * (1.0f - wy);
    sw[t][2] = (1.0f - wx) * wy;          sw[t][3] = wx * wy;
  }
  __syncthreads();
  int lane = t & 63, wv = t >> 6;
  for (int ii = wv; ii < 20; ii += 4) {
    int i = i_base + ii;
    float w00 = sw[ii][0], w01 = sw[ii][1], w10 = sw[ii][2], w11 = sw[ii][3];
    ushort2 u00 = ((const ushort2*)(aT + (size_t)sp[ii][0] * C1N))[lane];
    ushort2 u01 = ((const ushort2*)(aT + (size_t)sp[ii][1] * C1N))[lane];
    ushort2 u10 = ((const ushort2*)(aT + (size_t)sp[ii][2] * C1N))[lane];
    ushort2 u11 = ((const ushort2*)(aT + (size_t)sp[ii][3] * C1N))[lane];
    float v0 = w00 * bf2f(u00.x) + w01 * bf2f(u01.x) + w10 * bf2f(u10.x) + w11 * bf2f(u11.x);
    float v1 = w00 * bf2f(u00.y) + w01 * bf2f(u01.y) + w10 * bf2f(u10.y) + w11 * bf2f(u11.y);
    ushort2 outv; outv.x = f2bf(v0); outv.y = f2bf(v1);
    ((ushort2*)(aseq + (size_t)(j * GH + i) * C1N))[lane] = outv;
  }
}

// b (128,100,360) -> bs[(j*100+kk)*128 + c] (bf16)
__global__ __launch_bounds__(256) void transpose_k(const float* __restrict__ b,
                                                   __hip_bfloat16* __restrict__ bs) {
  __shared__ float tile[32][33];
  int kk = blockIdx.z;
  int j0 = blockIdx.x * 32, c0 = blockIdx.y * 32;
  int tj = threadIdx.x & 31;
  int tr = threadIdx.x >> 5;
  for (int cc = tr; cc < 32; cc += 8) {
    int gj = j0 + tj;
    tile[cc][tj] = (gj < WBB) ? b[(c0 + cc) * (HBB * WBB) + kk * WBB + gj] : 0.0f;
  }
  __syncthreads();
  for (int jj = tr; jj < 32; jj += 8) {
    int gj = j0 + jj;
    if (gj < WBB)
      bs[(size_t)(gj * HBB + kk) * C1N + c0 + (threadIdx.x & 31)] =
          __float2bfloat16(tile[threadIdx.x & 31][jj]);
  }
}

// Shared MFMA core: one wave computes 16 rows x 128 cols, K=128.
// Block = 256 threads = 4 waves = 64 rows. acc[8] = 32 VGPRs.
__device__ __forceinline__ void gemm16_mfma(const unsigned short* __restrict__ A,
                                            const unsigned short* __restrict__ W,
                                            int m_base, f32x4 acc[8]) {
  int lane = threadIdx.x & 63;
  int col = lane & 15, quad = lane >> 4;
#pragma unroll
  for (int nt = 0; nt < 8; ++nt) acc[nt] = (f32x4)0.0f;
#pragma unroll
  for (int s = 0; s < 4; ++s) {
    short8 aF = *(const short8*)&A[(size_t)(m_base + col) * 128 + s * 32 + quad * 8];
#pragma unroll
    for (int nt = 0; nt < 8; ++nt) {
      short8 bF = *(const short8*)&W[(size_t)(nt * 16 + col) * 128 + s * 32 + quad * 8];
      acc[nt] = __builtin_amdgcn_mfma_f32_16x16x32_bf16(aF, bF, acc[nt], 0, 0, 0);
    }
  }
}

// Stage the block's 64x128 bf16 output into LDS (MFMA lane layout -> row-major).
// tile rows padded to 136 shorts (272 B: 16B-aligned rows for b128 reads).
__device__ __forceinline__ void stage_bf16(unsigned short (*tile)[136],
                                           const f32x4 acc[8],
                                           const float* __restrict__ bias) {
  int lane = threadIdx.x & 63, wv = threadIdx.x >> 6;
  int col = lane & 15, quad = lane >> 4;
#pragma unroll
  for (int nt = 0; nt < 8; ++nt) {
    float bb = bias[nt * 16 + col];
#pragma unroll
    for (int r = 0; r < 4; ++r)
      tile[wv * 16 + quad * 4 + r][nt * 16 + col] = f2bf(acc[nt][r] + bb);
  }
  __syncthreads();
}

// q' -> qb row-major bf16. M = 72000 = 1125 * 64 exactly (no tail).
// Coalesced store: 16B/lane, 256B per row segment.
__global__ __launch_bounds__(256) void gemm_q_k(const unsigned short* __restrict__ A,
                                                const unsigned short* __restrict__ Wb,
                                                const float* __restrict__ beff,
                                                unsigned short* __restrict__ qb) {
  __shared__ unsigned short tile[64][136];
  int m0 = blockIdx.x * 64;
  f32x4 acc[8];
  gemm16_mfma(A, Wb, m0 + (threadIdx.x >> 6) * 16, acc);
  stage_bf16(tile, acc, beff);
  for (int u = threadIdx.x; u < 1024; u += 256) {
    int rl = u >> 4, ch = (u & 15) * 8;
    *(short8*)&qb[(size_t)(m0 + rl) * 128 + ch] = *(const short8*)&tile[rl][ch];
  }
}

// k' -> kb [j][key(pad128)][col] and v' -> vT [j][col][key(pad128)], fused.
// Grid (563, 2); M = 36000, last block rows 35968..36031 -> guard row<M.
// Tail A-reads (rows to 36031) stay inside the P1 allocation (36096 rows);
// 0xAA poison = -3e-13 bf16 is benign in MFMA. Stores only touch real keys, so
// kb/vT pad keys 100..127 keep their benign poison (NaN-reinterp hazard).
// kb store: 256B contiguous per key row. vT store: lanes cover 64 consecutive
// keys -> 128B contiguous per wave-instr (splits only at the j=100 wrap).
__global__ __launch_bounds__(256) void gemm_kv_k(const unsigned short* __restrict__ A,
                                                 const unsigned short* __restrict__ Wb,
                                                 const float* __restrict__ beff,
                                                 unsigned short* __restrict__ kb,
                                                 unsigned short* __restrict__ vT) {
  __shared__ unsigned short tile[64][136];
  int which = blockIdx.y;
  int m0 = blockIdx.x * 64;
  f32x4 acc[8];
  gemm16_mfma(A, Wb + (which ? 32768 : 16384), m0 + (threadIdx.x >> 6) * 16, acc);
  stage_bf16(tile, acc, beff + (which ? 256 : 128));
  if (which == 0) {
    for (int u = threadIdx.x; u < 1024; u += 256) {
      int rl = u >> 4, ch = (u & 15) * 8;
      int row = m0 + rl;
      if (row < 36000) {
        int jj = row / 100, key = row - jj * 100;
        *(short8*)&kb[((size_t)jj * 128 + key) * 128 + ch] = *(const short8*)&tile[rl][ch];
      }
    }
  } else {
    for (int u = threadIdx.x; u < 8192; u += 256) {
      int cc = u >> 6, kl = u & 63;
      int row = m0 + kl;
      if (row < 36000) {
        int jj = row / 100, key = row - jj * 100;
        vT[((size_t)jj * 128 + cc) * 128 + key] = tile[kl][cc];
      }
    }
  }
}

// out-projection o @ Wout^T + b -> a_enh f32. M = 72000 (no tail).
// f32 LDS tile, rows padded to 132 floats (528 B, 16B-aligned).
// Coalesced store: 16B/lane, 512B per row segment.
__global__ __launch_bounds__(256) void gemm_o_k(const unsigned short* __restrict__ A,
                                                const unsigned short* __restrict__ Wb,
                                                const float* __restrict__ beff,
                                                float* __restrict__ C) {
  __shared__ float tile[64][132];
  int m0 = blockIdx.x * 64;
  f32x4 acc[8];
  gemm16_mfma(A, Wb + 49152, m0 + (threadIdx.x >> 6) * 16, acc);
  {
    int lane = threadIdx.x & 63, wv = threadIdx.x >> 6;
    int col = lane & 15, quad = lane >> 4;
#pragma unroll
    for (int nt = 0; nt < 8; ++nt) {
      float bb = beff[384 + nt * 16 + col];
#pragma unroll
      for (int r = 0; r < 4; ++r)
        tile[wv * 16 + quad * 4 + r][nt * 16 + col] = acc[nt][r] + bb;
    }
  }
  __syncthreads();
  for (int u = threadIdx.x; u < 2048; u += 256) {
    int rl = u >> 5, ch = (u & 31) * 4;
    *(f32x4*)&C[(size_t)(m0 + rl) * 128 + ch] = *(const f32x4*)&tile[rl][ch];
  }
}

// MFMA attention v5. Block = 512 threads = 8 waves = (j, mt of 32 q rows);
// wave h handles head h. Grid (7, 360), x fastest so the 7 blocks sharing a
// j's kb/vT slice are dispatch-adjacent (L2-hot). The 8 waves collectively
// read all 128 chans of each qb/kb row (64B sector per wave) -> no sector
// over-fetch (attn4's 1-wave-per-head blocks fetched 2x).
// Swapped QK^T: S' = mfma(K, Q) puts a full P-row in each lane (col = qrow,
// regs = keys); P normalized in-register (row-sum = VALU + one lane^32
// shuffle), packed via v_cvt_pk_bf16_f32, stored as b64.
// Ps row stride = 120 shorts = 15 16B-chunks: chunk-slot (15*col+2*ks+half)%8
// covers all 8 slots -> conflict-free ds_read_b128 (writes 2-way = free).
// O staged in Osh then stored as full 256B rows (kills 2B scattered stores).
// qb: [j*200+q][chan] ; kb: [j][key(pad128)][chan] ; vT: [j][chan][key(pad128)]
// Pad keys 100..127 of kb/vT must stay benign (harness 0xAA poison = -3e-13):
// P is exactly 0.0 for keys 100..111, so pad-V contributes 0 (no NaN as long
// as accP aliasing never touches kb/vT — layout unchanged). mt=6 tail reads
// rows up to 72023 < 72192 allocated (poison benign); stores guarded qr<200.
__global__ __launch_bounds__(512) void attn5_k(const unsigned short* __restrict__ qb,
                                               const unsigned short* __restrict__ kb,
                                               const unsigned short* __restrict__ vT,
                                               unsigned short* __restrict__ o) {
  __shared__ unsigned short Ps[8][32][120];  // 61440 B
  __shared__ unsigned short Osh[32][136];    // 8704 B
  int mt = blockIdx.x, j = blockIdx.y;
  int h = threadIdx.x >> 6;
  int lane = threadIdx.x & 63;
  int col = lane & 31, half = lane >> 5;

  // ---- S' = K Q^T (A: key rows, B: q rows; K=16=head_dim) ----
  // S[nt][r] = S_raw[key = nt*32 + (r&3)+8*(r>>2)+4*half][qrow = col]
  short8 qF = *(const short8*)&qb[(size_t)(j * 200 + mt * 32 + col) * 128 + h * 16 + half * 8];
  f32x16 S[4];
#pragma unroll
  for (int nt = 0; nt < 4; ++nt) {
    short8 kF = *(const short8*)&kb[((size_t)j * 128 + nt * 32 + col) * 128 + h * 16 + half * 8];
    S[nt] = __builtin_amdgcn_mfma_f32_32x32x16_bf16(kF, qF, (f32x16)0.0f, 0, 0, 0);
  }

  // ---- exp + key mask (compile-time: nt<3 all valid; nt=3 valid iff half==0 && r<4) ----
  float rsum = 0.0f;
#pragma unroll
  for (int nt = 0; nt < 3; ++nt)
#pragma unroll
    for (int r = 0; r < 16; ++r) {
      float e = __expf(S[nt][r] * 0.25f);
      S[nt][r] = e; rsum += e;
    }
#pragma unroll
  for (int r = 0; r < 16; ++r) {
    float e = (half == 0 && r < 4) ? __expf(S[3][r] * 0.25f) : 0.0f;
    S[3][r] = e; rsum += e;
  }
  // lane pair (lane, lane^32) holds complementary key halves of the same qrow
  rsum += __shfl_xor(rsum, 32, 64);
  float inv = __fdividef(1.0f, rsum);

  // ---- normalize, pack pairs, store P row-major [qrow][key] as b64 groups ----
  // group (nt,g): keys nt*32 + 8*g + 4*half + {0..3} = regs 4*g + {0..3}
#pragma unroll
  for (int nt = 0; nt < 4; ++nt) {
#pragma unroll
    for (int g = 0; g < 4; ++g) {
      if (nt == 3 && g >= 2) continue;  // keys 112..127 never read by PV
      float e0 = S[nt][4 * g + 0] * inv, e1 = S[nt][4 * g + 1] * inv;
      float e2 = S[nt][4 * g + 2] * inv, e3 = S[nt][4 * g + 3] * inv;
      unsigned int lo, hi;
      asm("v_cvt_pk_bf16_f32 %0, %1, %2" : "=v"(lo) : "v"(e0), "v"(e1));
      asm("v_cvt_pk_bf16_f32 %0, %1, %2" : "=v"(hi) : "v"(e2), "v"(e3));
      *(uint2*)&Ps[h][col][nt * 32 + 8 * g + 4 * half] = make_uint2(lo, hi);
    }
  }

  // ---- O = P V  (keys 0..111; P already normalized; cols>=16 benign ones) ----
  short8 ones;
#pragma unroll
  for (int i = 0; i < 8; ++i) ones[i] = (short)0x3F80;
  const unsigned short* vrow = &vT[((size_t)j * 128 + h * 16 + (col & 15)) * 128];
  f32x16 O = (f32x16)0.0f;
#pragma unroll
  for (int ks = 0; ks < 7; ++ks) {
    short8 aP = *(const short8*)&Ps[h][col][ks * 16 + half * 8];
    short8 bV = (col < 16) ? *(const short8*)&vrow[ks * 16 + half * 8] : ones;
    O = __builtin_amdgcn_mfma_f32_32x32x16_bf16(aP, bV, O, 0, 0, 0);
  }
  // ---- stage O slice into Osh (cols 0..15 hold real chans for this head) ----
#pragma unroll
  for (int r = 0; r < 16; ++r) {
    int row = (r & 3) + 8 * (r >> 2) + 4 * half;
    if (col < 16) Osh[row][h * 16 + col] = f2bf(O[r]);
  }
  __syncthreads();
  // ---- coalesced store: 512 threads cover 32 rows x 16 chunks of 16B ----
  int rl = threadIdx.x >> 4, ch = (threadIdx.x & 15) * 8;
  int qr = mt * 32 + rl;
  if (qr < 200)
    *(short8*)&o[(size_t)(j * 200 + qr) * 128 + ch] = *(const short8*)&Osh[rl][ch];
}

// scatter-add a_enh into accP[p*128+c] (p-major) + cnt, run-merged.
// Grid (360, 4): block (j, y) owns i in [y*50, y*50+50). 256 threads =
// 128 channels x 2 halves of 25 rows. 5-wide load batches give ~5
// outstanding loads/wave. Run-merge split at block/half boundaries only
// adds a few atomics; atomicAdd semantics keep correctness across splits.
__global__ __launch_bounds__(256) void scatter3_k(const float* __restrict__ aenh,
                                                  const float* __restrict__ fovp, int n,
                                                  float* __restrict__ accP,
                                                  float* __restrict__ cnt) {
  __shared__ int sidx[50];
  int j = blockIdx.x;
  int i_base = blockIdx.y * 50;
  int t = threadIdx.x;
  float fov = fovp[n];
  if (t < 50) {
    float x, y;
    polar_xy(fov, i_base + t, j, x, y);
    int xi = (int)rintf(x); xi = max(0, min(199, xi));
    int yi = (int)rintf(y); yi = max(0, min(199, yi));
    sidx[t] = yi * 200 + xi;
    atomicAdd(&cnt[yi * 200 + xi], 1.0f);
  }
  __syncthreads();
  int c = t & 127;
  int half = t >> 7;
  int i0 = half * 25;
  const float* src = aenh + ((size_t)j * GH + i_base) * C1N + c;
  int cur = sidx[i0];
  float sum = 0.0f;
#pragma unroll
  for (int ib = 0; ib < 25; ib += 5) {
    float v[5];
#pragma unroll
    for (int u = 0; u < 5; ++u) v[u] = src[(size_t)(i0 + ib + u) * C1N];
#pragma unroll
    for (int u = 0; u < 5; ++u) {
      int idx = sidx[i0 + ib + u];
      if (idx != cur) {
        atomicAdd(&accP[(size_t)cur * C1N + c], sum);
        cur = idx;
        sum = v[u];
      } else {
        sum += v[u];
      }
    }
  }
  atomicAdd(&accP[(size_t)cur * C1N + c], sum);
}

// out = a + accP/cnt (LDS transpose, coalesced both sides).
__global__ __launch_bounds__(256) void finalize2_k(const float* __restrict__ a,
                                                   const float* __restrict__ accP,
                                                   const float* __restrict__ cnt,
                                                   float* __restrict__ out) {
  __shared__ float tile[64][129];
  __shared__ float sinv[64];
  int p0 = blockIdx.x * 64;
  int t = threadIdx.x;
  if (t < 64) {
    float cv = cnt[p0 + t];
    sinv[t] = 1.0f / (cv == 0.0f ? 1.0f : cv);
  }
  for (int u = t; u < 64 * 128; u += 256) {
    int pp = u >> 7, c = u & 127;
    tile[pp][c] = accP[(size_t)(p0 + pp) * C1N + c];
  }
  __syncthreads();
  for (int u = t; u < 64 * 128; u += 256) {
    int pp = u & 63, c = u >> 6;
    int g = c * 40000 + p0 + pp;
    out[g] = a[g] + tile[pp][c] * sinv[pp];
  }
}

extern "C" void kernel_launch(void* const* d_in, const int* in_sizes, int n_in,
                              void* d_out, int out_size, void* d_ws, size_t ws_size,
                              hipStream_t stream) {
  const float* list_a = (const float*)d_in[0];
  const float* list_b = (const float*)d_in[1];
  const float* fov   = (const float*)d_in[2];
  const float* Wq    = (const float*)d_in[5];
  const float* bq    = (const float*)d_in[6];
  const float* Wk    = (const float*)d_in[7];
  const float* bk    = (const float*)d_in[8];
  const float* Wv    = (const float*)d_in[9];
  const float* bv    = (const float*)d_in[10];
  const float* inw   = (const float*)d_in[11];
  const float* inb   = (const float*)d_in[12];
  const float* outw  = (const float*)d_in[13];
  const float* outb  = (const float*)d_in[14];
  float* out = (float*)d_out;
  float* ws = (float*)d_ws;

  // Layout (float units):
  // beff 512 | Wb 32768 | P2 9,216,000 (aT overlay -> a_enh f32)
  // | qb 4,620,288 | kb 2,949,120 | vT 2,949,120 | P0 4,620,288 (a_seq/o bf16)
  // | P1 2,310,144 (b_seq bf16) | cnt 40,000.  Total ~107 MB.
  // accP (5,120,000) aliases P0+P1 (both dead at scatter time) — NOT kb/vT,
  // whose pad keys must keep benign poison across samples (NaN-reinterp hazard).
  float* beff = ws;
  __hip_bfloat16* Wb = (__hip_bfloat16*)(ws + 512);
  float* P2 = ws + 512 + 32768;
  float* qb_f = P2 + 9216000;
  float* kb_f = qb_f + 4620288;
  float* vT_f = kb_f + 2949120;
  float* P0_f = vT_f + 2949120;
  float* P1_f = P0_f + 4620288;
  float* cnt  = P1_f + 2310144;

  unsigned short* qb = (unsigned short*)qb_f;
  unsigned short* kb = (unsigned short*)kb_f;
  unsigned short* vT = (unsigned short*)vT_f;
  __hip_bfloat16* P0 = (__hip_bfloat16*)P0_f;
  __hip_bfloat16* P1 = (__hip_bfloat16*)P1_f;
  __hip_bfloat16* aT = (__hip_bfloat16*)P2;   // dead before a_enh written
  float* accP = P0_f;                          // P0 (o) + 0.5M of P1, dead by scatter

  weff_k<<<dim3(128, 4), 128, 0, stream>>>(Wq, Wk, Wv, bq, bk, bv, inw, inb, outw, outb, Wb, beff);

  for (int n = 0; n < 2; ++n) {
    const float* a_n = list_a + (size_t)n * C1N * HA * WA;
    const float* b_n = list_b + (size_t)n * C1N * HBB * WBB;
    float* out_n = out + (size_t)n * C1N * HA * WA;

    (void)hipMemsetAsync(cnt, 0, (size_t)HA * WA * sizeof(float), stream);

    transA_k<<<dim3(1250, 4), 256, 0, stream>>>(a_n, aT);
    bilinear2_k<<<dim3(GW, 10), 256, 0, stream>>>(aT, fov, n, P0);
    transpose_k<<<dim3(12, 4, 100), 256, 0, stream>>>(b_n, P1);
    gemm_kv_k<<<dim3(563, 2), 256, 0, stream>>>((const unsigned short*)P1,
                                                (const unsigned short*)Wb, beff, kb, vT);
    gemm_q_k<<<1125, 256, 0, stream>>>((const unsigned short*)P0,
                                       (const unsigned short*)Wb, beff, qb);
    attn5_k<<<dim3(7, GW), 512, 0, stream>>>(qb, kb, vT, (unsigned short*)P0);    // o -> P0
    gemm_o_k<<<1125, 256, 0, stream>>>((const unsigned short*)P0,
                                       (const unsigned short*)Wb, beff, P2);      // a_enh f32
    // P0 (o) and P1 (b_seq) dead now; reuse as the p-major accumulator
    (void)hipMemsetAsync(accP, 0, (size_t)HA * WA * C1N * sizeof(float), stream);
    scatter3_k<<<dim3(GW, 4), 256, 0, stream>>>(P2, fov, n, accP, cnt);
    finalize2_k<<<625, 256, 0, stream>>>(a_n, accP, cnt, out_n);
  }
}

// Round 6
// 507.491 us; speedup vs baseline: 1.0657x; 1.0657x over previous
//
#include <hip/hip_runtime.h>
#include <hip/hip_bf16.h>
#include <math.h>

#define C1N 128
#define HA 200
#define WA 200
#define HBB 100
#define WBB 360
#define GH 200
#define GW 360
#define NHD 8
#define HDD 16

typedef __attribute__((ext_vector_type(8))) short short8;
typedef __attribute__((ext_vector_type(4))) float f32x4;
typedef __attribute__((ext_vector_type(16))) float f32x16;

__device__ __forceinline__ float bf2f(unsigned short u) {
  union { unsigned int i; float f; } c; c.i = ((unsigned int)u) << 16; return c.f;
}
__device__ __forceinline__ unsigned short f2bf(float f) {
  __hip_bfloat16 h = __float2bfloat16(f);
  unsigned short u;
  __builtin_memcpy(&u, &h, sizeof(u));
  return u;
}

// ---- coordinate pipeline: must match numpy f32 op-for-op. ----
__device__ __forceinline__ void polar_xy(float fov, int i, int j, float& x, float& y) {
#pragma clang fp contract(off)
  float t = (float)j / 359.0f;
  float angle = -fov / 2.0f + fov * t;
  float ca = (float)cos((double)angle);
  float sa = (float)sin((double)angle);
  float rmax = fminf(100.0f / fabsf(ca), 100.0f / fabsf(sa));
  float r = ((float)i / 199.0f) * rmax;
  float xv = 100.0f + r * ca;
  float yv = 100.0f - r * sa;
  x = fminf(fmaxf(xv, 0.0f), 199.0f);
  y = fminf(fmaxf(yv, 0.0f), 199.0f);
}

// Fused weights in bf16: Wb[w<3] = (in_proj_w[w] @ {Wq,Wk,Wv}) ; Wb[3] = out_w.
__global__ void weff_k(const float* __restrict__ Wq, const float* __restrict__ Wk,
                       const float* __restrict__ Wv, const float* __restrict__ bq,
                       const float* __restrict__ bk, const float* __restrict__ bv,
                       const float* __restrict__ inw, const float* __restrict__ inb,
                       const float* __restrict__ outw, const float* __restrict__ outb,
                       __hip_bfloat16* __restrict__ Wb, float* __restrict__ beff) {
  int which = blockIdx.y;
  int o = blockIdx.x;
  int kcol = threadIdx.x;
  if (which == 3) {
    Wb[3 * 16384 + o * 128 + kcol] = __float2bfloat16(outw[o * 128 + kcol]);
    if (kcol == 0) beff[384 + o] = outb[o];
    return;
  }
  const float* Wx = (which == 0) ? Wq : ((which == 1) ? Wk : Wv);
  const float* bx = (which == 0) ? bq : ((which == 1) ? bk : bv);
  const float* wrow = inw + (which * 128 + o) * 128;
  float acc = 0.0f;
  for (int m = 0; m < 128; ++m) acc += wrow[m] * Wx[m * 128 + kcol];
  Wb[which * 16384 + o * 128 + kcol] = __float2bfloat16(acc);
  if (kcol == 0) {
    float bacc = inb[which * 128 + o];
    for (int m = 0; m < 128; ++m) bacc += wrow[m] * bx[m];
    beff[which * 128 + o] = bacc;
  }
}

// a (128,200,200) f32 -> aT[(y*200+x)*128 + c] bf16. LDS 32x32 tiles.
__global__ __launch_bounds__(256) void transA_k(const float* __restrict__ a,
                                                __hip_bfloat16* __restrict__ aT) {
  __shared__ float tile[32][33];
  int p0 = blockIdx.x * 32, c0 = blockIdx.y * 32;
  int tp = threadIdx.x & 31, tr = threadIdx.x >> 5;
  for (int cc = tr; cc < 32; cc += 8)
    tile[cc][tp] = a[(size_t)(c0 + cc) * 40000 + p0 + tp];
  __syncthreads();
  for (int pp = tr; pp < 32; pp += 8)
    aT[(size_t)(p0 + pp) * C1N + c0 + tp] = __float2bfloat16(tile[tp][pp]);
}

// Coalesced bilinear from aT (bf16 p-major).
__global__ __launch_bounds__(256) void bilinear2_k(const __hip_bfloat16* __restrict__ aT,
                                                   const float* __restrict__ fovp, int n,
                                                   __hip_bfloat16* __restrict__ aseq) {
  __shared__ float sw[20][4];
  __shared__ int sp[20][4];
  int j = blockIdx.x;
  int i_base = blockIdx.y * 20;
  int t = threadIdx.x;
  if (t < 20) {
    float x, y;
    polar_xy(fovp[n], i_base + t, j, x, y);
    float x0f = floorf(x), y0f = floorf(y);
    float wx = x - x0f, wy = y - y0f;
    int x0 = max(0, min(199, (int)x0f));
    int x1 = min(x0 + 1, 199);
    int y0 = max(0, min(199, (int)y0f));
    int y1 = min(y0 + 1, 199);
    sp[t][0] = y0 * 200 + x0; sp[t][1] = y0 * 200 + x1;
    sp[t][2] = y1 * 200 + x0; sp[t][3] = y1 * 200 + x1;
    sw[t][0] = (1.0f - wx) * (1.0f - wy); sw[t][1] = wx * (1.0f - wy);
    sw[t][2] = (1.0f - wx) * wy;          sw[t][3] = wx * wy;
  }
  __syncthreads();
  int lane = t & 63, wv = t >> 6;
  for (int ii = wv; ii < 20; ii += 4) {
    int i = i_base + ii;
    float w00 = sw[ii][0], w01 = sw[ii][1], w10 = sw[ii][2], w11 = sw[ii][3];
    ushort2 u00 = ((const ushort2*)(aT + (size_t)sp[ii][0] * C1N))[lane];
    ushort2 u01 = ((const ushort2*)(aT + (size_t)sp[ii][1] * C1N))[lane];
    ushort2 u10 = ((const ushort2*)(aT + (size_t)sp[ii][2] * C1N))[lane];
    ushort2 u11 = ((const ushort2*)(aT + (size_t)sp[ii][3] * C1N))[lane];
    float v0 = w00 * bf2f(u00.x) + w01 * bf2f(u01.x) + w10 * bf2f(u10.x) + w11 * bf2f(u11.x);
    float v1 = w00 * bf2f(u00.y) + w01 * bf2f(u01.y) + w10 * bf2f(u10.y) + w11 * bf2f(u11.y);
    ushort2 outv; outv.x = f2bf(v0); outv.y = f2bf(v1);
    ((ushort2*)(aseq + (size_t)(j * GH + i) * C1N))[lane] = outv;
  }
}

// b (128,100,360) -> bs[(j*100+kk)*128 + c] (bf16)
__global__ __launch_bounds__(256) void transpose_k(const float* __restrict__ b,
                                                   __hip_bfloat16* __restrict__ bs) {
  __shared__ float tile[32][33];
  int kk = blockIdx.z;
  int j0 = blockIdx.x * 32, c0 = blockIdx.y * 32;
  int tj = threadIdx.x & 31;
  int tr = threadIdx.x >> 5;
  for (int cc = tr; cc < 32; cc += 8) {
    int gj = j0 + tj;
    tile[cc][tj] = (gj < WBB) ? b[(c0 + cc) * (HBB * WBB) + kk * WBB + gj] : 0.0f;
  }
  __syncthreads();
  for (int jj = tr; jj < 32; jj += 8) {
    int gj = j0 + jj;
    if (gj < WBB)
      bs[(size_t)(gj * HBB + kk) * C1N + c0 + (threadIdx.x & 31)] =
          __float2bfloat16(tile[threadIdx.x & 31][jj]);
  }
}

// Shared MFMA core: one wave computes 16 rows x 128 cols, K=128.
// Block = 256 threads = 4 waves = 64 rows. acc[8] = 32 VGPRs.
__device__ __forceinline__ void gemm16_mfma(const unsigned short* __restrict__ A,
                                            const unsigned short* __restrict__ W,
                                            int m_base, f32x4 acc[8]) {
  int lane = threadIdx.x & 63;
  int col = lane & 15, quad = lane >> 4;
#pragma unroll
  for (int nt = 0; nt < 8; ++nt) acc[nt] = (f32x4)0.0f;
#pragma unroll
  for (int s = 0; s < 4; ++s) {
    short8 aF = *(const short8*)&A[(size_t)(m_base + col) * 128 + s * 32 + quad * 8];
#pragma unroll
    for (int nt = 0; nt < 8; ++nt) {
      short8 bF = *(const short8*)&W[(size_t)(nt * 16 + col) * 128 + s * 32 + quad * 8];
      acc[nt] = __builtin_amdgcn_mfma_f32_16x16x32_bf16(aF, bF, acc[nt], 0, 0, 0);
    }
  }
}

// Stage the block's 64x128 bf16 output into LDS (MFMA lane layout -> row-major).
// tile rows padded to 136 shorts (272 B: 16B-aligned rows for b128 reads).
__device__ __forceinline__ void stage_bf16(unsigned short (*tile)[136],
                                           const f32x4 acc[8],
                                           const float* __restrict__ bias) {
  int lane = threadIdx.x & 63, wv = threadIdx.x >> 6;
  int col = lane & 15, quad = lane >> 4;
#pragma unroll
  for (int nt = 0; nt < 8; ++nt) {
    float bb = bias[nt * 16 + col];
#pragma unroll
    for (int r = 0; r < 4; ++r)
      tile[wv * 16 + quad * 4 + r][nt * 16 + col] = f2bf(acc[nt][r] + bb);
  }
  __syncthreads();
}

// q' -> qb row-major bf16. M = 72000 = 1125 * 64 exactly (no tail).
// Coalesced store: 16B/lane, 256B per row segment.
__global__ __launch_bounds__(256) void gemm_q_k(const unsigned short* __restrict__ A,
                                                const unsigned short* __restrict__ Wb,
                                                const float* __restrict__ beff,
                                                unsigned short* __restrict__ qb) {
  __shared__ unsigned short tile[64][136];
  int m0 = blockIdx.x * 64;
  f32x4 acc[8];
  gemm16_mfma(A, Wb, m0 + (threadIdx.x >> 6) * 16, acc);
  stage_bf16(tile, acc, beff);
  for (int u = threadIdx.x; u < 1024; u += 256) {
    int rl = u >> 4, ch = (u & 15) * 8;
    *(short8*)&qb[(size_t)(m0 + rl) * 128 + ch] = *(const short8*)&tile[rl][ch];
  }
}

// k' -> kb [j][key(pad128)][col] and v' -> vT [j][col][key(pad128)], fused.
// Grid (563, 2); M = 36000, last block rows 35968..36031 -> guard row<M.
// Tail A-reads (rows to 36031) stay inside the P1 allocation (36096 rows);
// 0xAA poison = -3e-13 bf16 is benign in MFMA. Stores only touch real keys, so
// kb/vT pad keys 100..127 keep their benign poison (NaN-reinterp hazard).
// kb store: 256B contiguous per key row. vT store: lanes cover 64 consecutive
// keys -> 128B contiguous per wave-instr (splits only at the j=100 wrap).
__global__ __launch_bounds__(256) void gemm_kv_k(const unsigned short* __restrict__ A,
                                                 const unsigned short* __restrict__ Wb,
                                                 const float* __restrict__ beff,
                                                 unsigned short* __restrict__ kb,
                                                 unsigned short* __restrict__ vT) {
  __shared__ unsigned short tile[64][136];
  int which = blockIdx.y;
  int m0 = blockIdx.x * 64;
  f32x4 acc[8];
  gemm16_mfma(A, Wb + (which ? 32768 : 16384), m0 + (threadIdx.x >> 6) * 16, acc);
  stage_bf16(tile, acc, beff + (which ? 256 : 128));
  if (which == 0) {
    for (int u = threadIdx.x; u < 1024; u += 256) {
      int rl = u >> 4, ch = (u & 15) * 8;
      int row = m0 + rl;
      if (row < 36000) {
        int jj = row / 100, key = row - jj * 100;
        *(short8*)&kb[((size_t)jj * 128 + key) * 128 + ch] = *(const short8*)&tile[rl][ch];
      }
    }
  } else {
    for (int u = threadIdx.x; u < 8192; u += 256) {
      int cc = u >> 6, kl = u & 63;
      int row = m0 + kl;
      if (row < 36000) {
        int jj = row / 100, key = row - jj * 100;
        vT[((size_t)jj * 128 + cc) * 128 + key] = tile[kl][cc];
      }
    }
  }
}

// MFMA attention v6 = v5 body + XCD-aware block remap.
// Grid 2520 1D. Consecutive linear block IDs round-robin across the 8 XCDs
// (each with a private L2), so decode d -> (j, mt) such that all 7 mt-blocks
// of a given j share d mod 8 == j/45 -> SAME XCD -> kb/vT fetched once per j
// (attn5's (7,360) grid put the 7 same-j blocks on 7 DIFFERENT XCDs: 90 MB
// FETCH vs the ~45 MB ideal). 45 j-slices per XCD x ~60 KB each: L2-resident.
// qb: [j*200+q][chan] ; kb: [j][key(pad128)][chan] ; vT: [j][chan][key(pad128)]
// Pad keys 100..127 of kb/vT must stay benign (harness 0xAA poison = -3e-13):
// P is exactly 0.0 for keys 100..111, so pad-V contributes 0 (no NaN as long
// as nothing overwrites kb/vT pads). mt=6 tail reads rows up to 72023 < 72192
// allocated (poison benign); stores guarded qr<200.
__global__ __launch_bounds__(512) void attn6_k(const unsigned short* __restrict__ qb,
                                               const unsigned short* __restrict__ kb,
                                               const unsigned short* __restrict__ vT,
                                               unsigned short* __restrict__ o) {
  __shared__ unsigned short Ps[8][32][120];  // 61440 B
  __shared__ unsigned short Osh[32][136];    // 8704 B
  int d = blockIdx.x;
  int xcd = d & 7, idx = d >> 3;            // idx in [0,315)
  int j = xcd * 45 + idx % 45;              // bijective: (j,mt) covered once
  int mt = idx / 45;
  int h = threadIdx.x >> 6;
  int lane = threadIdx.x & 63;
  int col = lane & 31, half = lane >> 5;

  // ---- S' = K Q^T (A: key rows, B: q rows; K=16=head_dim) ----
  // S[nt][r] = S_raw[key = nt*32 + (r&3)+8*(r>>2)+4*half][qrow = col]
  short8 qF = *(const short8*)&qb[(size_t)(j * 200 + mt * 32 + col) * 128 + h * 16 + half * 8];
  f32x16 S[4];
#pragma unroll
  for (int nt = 0; nt < 4; ++nt) {
    short8 kF = *(const short8*)&kb[((size_t)j * 128 + nt * 32 + col) * 128 + h * 16 + half * 8];
    S[nt] = __builtin_amdgcn_mfma_f32_32x32x16_bf16(kF, qF, (f32x16)0.0f, 0, 0, 0);
  }

  // ---- exp + key mask (compile-time: nt<3 all valid; nt=3 valid iff half==0 && r<4) ----
  float rsum = 0.0f;
#pragma unroll
  for (int nt = 0; nt < 3; ++nt)
#pragma unroll
    for (int r = 0; r < 16; ++r) {
      float e = __expf(S[nt][r] * 0.25f);
      S[nt][r] = e; rsum += e;
    }
#pragma unroll
  for (int r = 0; r < 16; ++r) {
    float e = (half == 0 && r < 4) ? __expf(S[3][r] * 0.25f) : 0.0f;
    S[3][r] = e; rsum += e;
  }
  // lane pair (lane, lane^32) holds complementary key halves of the same qrow
  rsum += __shfl_xor(rsum, 32, 64);
  float inv = __fdividef(1.0f, rsum);

  // ---- normalize, pack pairs, store P row-major [qrow][key] as b64 groups ----
  // group (nt,g): keys nt*32 + 8*g + 4*half + {0..3} = regs 4*g + {0..3}
#pragma unroll
  for (int nt = 0; nt < 4; ++nt) {
#pragma unroll
    for (int g = 0; g < 4; ++g) {
      if (nt == 3 && g >= 2) continue;  // keys 112..127 never read by PV
      float e0 = S[nt][4 * g + 0] * inv, e1 = S[nt][4 * g + 1] * inv;
      float e2 = S[nt][4 * g + 2] * inv, e3 = S[nt][4 * g + 3] * inv;
      unsigned int lo, hi;
      asm("v_cvt_pk_bf16_f32 %0, %1, %2" : "=v"(lo) : "v"(e0), "v"(e1));
      asm("v_cvt_pk_bf16_f32 %0, %1, %2" : "=v"(hi) : "v"(e2), "v"(e3));
      *(uint2*)&Ps[h][col][nt * 32 + 8 * g + 4 * half] = make_uint2(lo, hi);
    }
  }

  // ---- O = P V  (keys 0..111; P already normalized; cols>=16 benign ones) ----
  short8 ones;
#pragma unroll
  for (int i = 0; i < 8; ++i) ones[i] = (short)0x3F80;
  const unsigned short* vrow = &vT[((size_t)j * 128 + h * 16 + (col & 15)) * 128];
  f32x16 O = (f32x16)0.0f;
#pragma unroll
  for (int ks = 0; ks < 7; ++ks) {
    short8 aP = *(const short8*)&Ps[h][col][ks * 16 + half * 8];
    short8 bV = (col < 16) ? *(const short8*)&vrow[ks * 16 + half * 8] : ones;
    O = __builtin_amdgcn_mfma_f32_32x32x16_bf16(aP, bV, O, 0, 0, 0);
  }
  // ---- stage O slice into Osh (cols 0..15 hold real chans for this head) ----
#pragma unroll
  for (int r = 0; r < 16; ++r) {
    int row = (r & 3) + 8 * (r >> 2) + 4 * half;
    if (col < 16) Osh[row][h * 16 + col] = f2bf(O[r]);
  }
  __syncthreads();
  // ---- coalesced store: 512 threads cover 32 rows x 16 chunks of 16B ----
  int rl = threadIdx.x >> 4, ch = (threadIdx.x & 15) * 8;
  int qr = mt * 32 + rl;
  if (qr < 200)
    *(short8*)&o[(size_t)(j * 200 + qr) * 128 + ch] = *(const short8*)&Osh[rl][ch];
}

// Fused out-projection + scatter: C = o @ Wout^T + b computed into an LDS f32
// tile, pixel indices computed per row (each row m = j*200+i evaluated exactly
// once since blocks partition m), cnt bumped, then a run-merged atomicAdd walk
// over the LDS tile into accP (p-major). Kills the 74 MB a_enh HBM round-trip
// and the separate scatter dispatch. M = 72000 = 1125*64 (no tail).
// accP must NOT alias A (=P0/o): it lives in P2 (aT dead by now).
__global__ __launch_bounds__(256) void gemm_os_k(const unsigned short* __restrict__ A,
                                                 const unsigned short* __restrict__ Wb,
                                                 const float* __restrict__ beff,
                                                 const float* __restrict__ fovp, int n,
                                                 float* __restrict__ accP,
                                                 float* __restrict__ cnt) {
  __shared__ float tile[64][132];
  __shared__ int sidx[64];
  int m0 = blockIdx.x * 64;
  int t = threadIdx.x;
  f32x4 acc[8];
  gemm16_mfma(A, Wb + 49152, m0 + (t >> 6) * 16, acc);
  if (t < 64) {
    int m = m0 + t;
    int j = m / 200, i = m - j * 200;
    float x, y;
    polar_xy(fovp[n], i, j, x, y);
    int xi = (int)rintf(x); xi = max(0, min(199, xi));
    int yi = (int)rintf(y); yi = max(0, min(199, yi));
    sidx[t] = yi * 200 + xi;
    atomicAdd(&cnt[yi * 200 + xi], 1.0f);
  }
  {
    int lane = t & 63, wv = t >> 6;
    int col = lane & 15, quad = lane >> 4;
#pragma unroll
    for (int nt = 0; nt < 8; ++nt) {
      float bb = beff[384 + nt * 16 + col];
#pragma unroll
      for (int r = 0; r < 4; ++r)
        tile[wv * 16 + quad * 4 + r][nt * 16 + col] = acc[nt][r] + bb;
    }
  }
  __syncthreads();
  // run-merged scatter: 256 threads = 128 channels x 2 halves of 32 rows.
  // LDS reads are conflict-free (64 consecutive c per wave -> 2 lanes/bank).
  // Merge split at half/block boundaries only adds a few atomics; atomicAdd
  // keeps correctness across any split.
  int c = t & 127, half = t >> 7;
  int r0 = half * 32;
  int cur = sidx[r0];
  float sum = 0.0f;
#pragma unroll 4
  for (int r = r0; r < r0 + 32; ++r) {
    float v = tile[r][c];
    int idx = sidx[r];
    if (idx != cur) {
      atomicAdd(&accP[(size_t)cur * C1N + c], sum);
      cur = idx;
      sum = v;
    } else {
      sum += v;
    }
  }
  atomicAdd(&accP[(size_t)cur * C1N + c], sum);
}

// out = a + accP/cnt (LDS transpose, coalesced both sides).
__global__ __launch_bounds__(256) void finalize2_k(const float* __restrict__ a,
                                                   const float* __restrict__ accP,
                                                   const float* __restrict__ cnt,
                                                   float* __restrict__ out) {
  __shared__ float tile[64][129];
  __shared__ float sinv[64];
  int p0 = blockIdx.x * 64;
  int t = threadIdx.x;
  if (t < 64) {
    float cv = cnt[p0 + t];
    sinv[t] = 1.0f / (cv == 0.0f ? 1.0f : cv);
  }
  for (int u = t; u < 64 * 128; u += 256) {
    int pp = u >> 7, c = u & 127;
    tile[pp][c] = accP[(size_t)(p0 + pp) * C1N + c];
  }
  __syncthreads();
  for (int u = t; u < 64 * 128; u += 256) {
    int pp = u & 63, c = u >> 6;
    int g = c * 40000 + p0 + pp;
    out[g] = a[g] + tile[pp][c] * sinv[pp];
  }
}

extern "C" void kernel_launch(void* const* d_in, const int* in_sizes, int n_in,
                              void* d_out, int out_size, void* d_ws, size_t ws_size,
                              hipStream_t stream) {
  const float* list_a = (const float*)d_in[0];
  const float* list_b = (const float*)d_in[1];
  const float* fov   = (const float*)d_in[2];
  const float* Wq    = (const float*)d_in[5];
  const float* bq    = (const float*)d_in[6];
  const float* Wk    = (const float*)d_in[7];
  const float* bk    = (const float*)d_in[8];
  const float* Wv    = (const float*)d_in[9];
  const float* bv    = (const float*)d_in[10];
  const float* inw   = (const float*)d_in[11];
  const float* inb   = (const float*)d_in[12];
  const float* outw  = (const float*)d_in[13];
  const float* outb  = (const float*)d_in[14];
  float* out = (float*)d_out;
  float* ws = (float*)d_ws;

  // Layout (float units):
  // beff 512 | Wb 32768 | P2 9,216,000 (aT overlay; later accP p-major f32)
  // | qb 4,620,288 | kb 2,949,120 | vT 2,949,120 | P0 4,620,288 (a_seq/o bf16)
  // | P1 2,310,144 (b_seq bf16) | cnt 40,000.  Total ~107 MB.
  // accP (5,120,000 f32) now lives in P2: aT (first 2.56M floats as bf16) is
  // dead once bilinear2 completes, and gemm_os reads A=P0 while atomically
  // writing accP -> accP must NOT alias P0 (old scheme would race).
  // kb/vT pad keys keep benign poison across samples (NaN-reinterp hazard).
  float* beff = ws;
  __hip_bfloat16* Wb = (__hip_bfloat16*)(ws + 512);
  float* P2 = ws + 512 + 32768;
  float* qb_f = P2 + 9216000;
  float* kb_f = qb_f + 4620288;
  float* vT_f = kb_f + 2949120;
  float* P0_f = vT_f + 2949120;
  float* P1_f = P0_f + 4620288;
  float* cnt  = P1_f + 2310144;

  unsigned short* qb = (unsigned short*)qb_f;
  unsigned short* kb = (unsigned short*)kb_f;
  unsigned short* vT = (unsigned short*)vT_f;
  __hip_bfloat16* P0 = (__hip_bfloat16*)P0_f;
  __hip_bfloat16* P1 = (__hip_bfloat16*)P1_f;
  __hip_bfloat16* aT = (__hip_bfloat16*)P2;   // dead after bilinear2
  float* accP = P2;                            // reuses P2 after aT is dead

  weff_k<<<dim3(128, 4), 128, 0, stream>>>(Wq, Wk, Wv, bq, bk, bv, inw, inb, outw, outb, Wb, beff);

  for (int n = 0; n < 2; ++n) {
    const float* a_n = list_a + (size_t)n * C1N * HA * WA;
    const float* b_n = list_b + (size_t)n * C1N * HBB * WBB;
    float* out_n = out + (size_t)n * C1N * HA * WA;

    (void)hipMemsetAsync(cnt, 0, (size_t)HA * WA * sizeof(float), stream);

    transA_k<<<dim3(1250, 4), 256, 0, stream>>>(a_n, aT);
    bilinear2_k<<<dim3(GW, 10), 256, 0, stream>>>(aT, fov, n, P0);
    // aT dead now; zero accP (same P2 region) before the fused scatter.
    (void)hipMemsetAsync(accP, 0, (size_t)HA * WA * C1N * sizeof(float), stream);
    transpose_k<<<dim3(12, 4, 100), 256, 0, stream>>>(b_n, P1);
    gemm_kv_k<<<dim3(563, 2), 256, 0, stream>>>((const unsigned short*)P1,
                                                (const unsigned short*)Wb, beff, kb, vT);
    gemm_q_k<<<1125, 256, 0, stream>>>((const unsigned short*)P0,
                                       (const unsigned short*)Wb, beff, qb);
    attn6_k<<<2520, 512, 0, stream>>>(qb, kb, vT, (unsigned short*)P0);   // o -> P0
    gemm_os_k<<<1125, 256, 0, stream>>>((const unsigned short*)P0,
                                        (const unsigned short*)Wb, beff, fov, n,
                                        accP, cnt);                        // scatter fused
    finalize2_k<<<625, 256, 0, stream>>>(a_n, accP, cnt, out_n);
  }
}